// Round 4
// baseline (95.462 us; speedup 1.0000x reference)
//
#include <hip/hip_runtime.h>

namespace {

constexpr int NQ = 10;

struct cplx { float re, im; };

__device__ __forceinline__ cplx cmul(cplx a, cplx b) {
  return cplx{ fmaf(a.re, b.re, -a.im * b.im), fmaf(a.re, b.im, a.im * b.re) };
}
// u*a + v*b (complex), 8 scalar FMA
__device__ __forceinline__ cplx cmadd2(cplx u, cplx a, cplx v, cplx b) {
  cplx r;
  r.re = fmaf(u.re, a.re, fmaf(-u.im, a.im, fmaf(v.re, b.re, -v.im * b.im)));
  r.im = fmaf(u.re, a.im, fmaf( u.im, a.re, fmaf(v.re, b.im,  v.im * b.re)));
  return r;
}
__device__ __forceinline__ cplx csel(bool c, cplx x, cplx y) {
  return cplx{ c ? x.re : y.re, c ? x.im : y.im };
}

__device__ __forceinline__ float fast_tanh(float x) {
  float xc = fminf(fmaxf(x, -10.f), 10.f);
  float e = __expf(2.f * xc);
  return __fdividef(e - 1.f, e + 1.f);
}

// ---- cross-lane primitives ----
__device__ __forceinline__ float rdlane(float v, int l) {
  return __int_as_float(__builtin_amdgcn_readlane(__float_as_int(v), l));
}
// DPP: quad_perm xor1=0xB1 xor2=0x4E xor3=0x1B; row_ror:8=0x128 (xor8);
// row_mirror=0x140 (xor15); row_half_mirror=0x141 (xor7)
template<int CTRL>
__device__ __forceinline__ float dppf(float v) {
  return __int_as_float(__builtin_amdgcn_update_dpp(0, __float_as_int(v), CTRL, 0xF, 0xF, true));
}
template<int CTRL>
__device__ __forceinline__ cplx dppc(cplx v) { return cplx{ dppf<CTRL>(v.re), dppf<CTRL>(v.im) }; }
template<int C1, int C2>
__device__ __forceinline__ cplx dppc2(cplx v) { return dppc<C2>(dppc<C1>(v)); }

template<int PAT>   // ds_swizzle BitMode: (xor<<10)|(or<<5)|and
__device__ __forceinline__ float swzf(float v) {
  return __int_as_float(__builtin_amdgcn_ds_swizzle(__float_as_int(v), PAT));
}
template<int PAT>
__device__ __forceinline__ cplx swzc(cplx v) { return cplx{ swzf<PAT>(v.re), swzf<PAT>(v.im) }; }
__device__ __forceinline__ cplx shflxc(cplx v, int m) {
  return cplx{ __shfl_xor(v.re, m), __shfl_xor(v.im, m) };
}

// ---- per-lane Rot matrices (lane g holds gate g), broadcast by readlane ----
struct Umat { float r00,i00,r01,i01,r10,i10,r11,i11; };
__device__ __forceinline__ void getU(const Umat& m, int g,
                                     cplx& u00, cplx& u01, cplx& u10, cplx& u11) {
  u00 = cplx{rdlane(m.r00, g), rdlane(m.i00, g)};
  u01 = cplx{rdlane(m.r01, g), rdlane(m.i01, g)};
  u10 = cplx{rdlane(m.r10, g), rdlane(m.i10, g)};
  u11 = cplx{rdlane(m.r11, g), rdlane(m.i11, g)};
}

// ---- gate templates (all three CNOT chains algebraically folded) ----
template<int LX, int HIL>
__device__ __forceinline__ void gate_shfl(cplx (&amp)[16], int lane, cplx u00,cplx u01,cplx u10,cplx u11) {
  bool hi = (__popc(lane & HIL) & 1) != 0;
  cplx cA = csel(hi, u11, u00), cB = csel(hi, u10, u01);
  #pragma unroll
  for (int t = 0; t < 16; ++t) amp[t] = cmadd2(cA, amp[t], cB, shflxc(amp[t], LX));
}
template<int PAT, int HIL>
__device__ __forceinline__ void gate_swz(cplx (&amp)[16], int lane, cplx u00,cplx u01,cplx u10,cplx u11) {
  bool hi = (__popc(lane & HIL) & 1) != 0;
  cplx cA = csel(hi, u11, u00), cB = csel(hi, u10, u01);
  #pragma unroll
  for (int t = 0; t < 16; ++t) amp[t] = cmadd2(cA, amp[t], cB, swzc<PAT>(amp[t]));
}
template<int C1, int HIL>
__device__ __forceinline__ void gate_dpp1(cplx (&amp)[16], int lane, cplx u00,cplx u01,cplx u10,cplx u11) {
  bool hi = (__popc(lane & HIL) & 1) != 0;
  cplx cA = csel(hi, u11, u00), cB = csel(hi, u10, u01);
  #pragma unroll
  for (int t = 0; t < 16; ++t) amp[t] = cmadd2(cA, amp[t], cB, dppc<C1>(amp[t]));
}
template<int C1, int C2, int HIL>
__device__ __forceinline__ void gate_dpp2(cplx (&amp)[16], int lane, cplx u00,cplx u01,cplx u10,cplx u11) {
  bool hi = (__popc(lane & HIL) & 1) != 0;
  cplx cA = csel(hi, u11, u00), cB = csel(hi, u10, u01);
  #pragma unroll
  for (int t = 0; t < 16; ++t) amp[t] = cmadd2(cA, amp[t], cB, dppc2<C1,C2>(amp[t]));
}
template<int CTRL, int LOCX, int HIL>
__device__ __forceinline__ void gate_mixed(cplx (&amp)[16], int lane, cplx u00,cplx u01,cplx u10,cplx u11) {
  bool hi = (__popc(lane & HIL) & 1) != 0;
  cplx cA = csel(hi, u11, u00), cB = csel(hi, u10, u01);
  #pragma unroll
  for (int t0 = 0; t0 < 16; ++t0) {
    if (t0 & LOCX) continue;
    const int t1 = t0 | LOCX;
    cplx o0 = dppc<CTRL>(amp[t1]);
    cplx o1 = dppc<CTRL>(amp[t0]);
    amp[t0] = cmadd2(cA, amp[t0], cB, o0);
    amp[t1] = cmadd2(cA, amp[t1], cB, o1);
  }
}
constexpr int hbit(int m) { return m >= 8 ? 8 : (m >= 4 ? 4 : (m >= 2 ? 2 : 1)); }
template<int PLOC, int HIL, int HILOC>
__device__ __forceinline__ void gate_local(cplx (&amp)[16], int lane, cplx u00,cplx u01,cplx u10,cplx u11) {
  bool h0 = (__popc(lane & HIL) & 1) != 0;
  cplx cA0 = csel(h0, u11, u00), cB0 = csel(h0, u10, u01);
  cplx cA1 = csel(h0, u00, u11), cB1 = csel(h0, u01, u10);
  #pragma unroll
  for (int ta = 0; ta < 16; ++ta) {
    if (ta & hbit(PLOC)) continue;
    const int tb = ta ^ PLOC;
    const bool pa = (__popc(ta & HILOC) & 1) != 0;   // compile-time
    cplx aA = amp[ta], aB = amp[tb];
    if (!pa) { amp[ta] = cmadd2(cA0, aA, cB0, aB); amp[tb] = cmadd2(cA1, aB, cB1, aA); }
    else     { amp[ta] = cmadd2(cA1, aA, cB1, aB); amp[tb] = cmadd2(cA0, aB, cB0, aA); }
  }
}

// 6-stage lane-space Walsh-Hadamard butterfly: lane m ends with
// sum_l v(l) * (-1)^popc(l & m). Only 2 DS ops (xor16 swizzle, xor32 bpermute).
__device__ __forceinline__ float wht6(float v, float s1, float s2, float s4,
                                      float s8, float s16, float s32) {
  float o;
  o = dppf<0xB1>(v);               v = fmaf(s1,  v, o);   // xor1
  o = dppf<0x4E>(v);               v = fmaf(s2,  v, o);   // xor2
  o = dppf<0x1B>(dppf<0x141>(v));  v = fmaf(s4,  v, o);   // xor4 = xor7 o xor3
  o = dppf<0x128>(v);              v = fmaf(s8,  v, o);   // xor8
  o = swzf<0x401F>(v);             v = fmaf(s16, v, o);   // xor16 (DS swizzle)
  o = __shfl_xor(v, 32);           v = fmaf(s32, v, o);   // xor32 (DS bpermute)
  return v;
}

__global__ __launch_bounds__(256, 4)
void qgan_kernel(const float* __restrict__ z, const float* __restrict__ wts,
                 const float* __restrict__ W1, const float* __restrict__ b1,
                 const float* __restrict__ W2, const float* __restrict__ b2,
                 const float* __restrict__ W3, const float* __restrict__ b3,
                 float* __restrict__ out, int B)
{
  const int tid  = blockIdx.x * 256 + threadIdx.x;
  const int lane = threadIdx.x & 63;
  const int wv   = __builtin_amdgcn_readfirstlane(tid >> 6);   // one elem per wave
  if (wv >= B) return;

  // ---- prefetch MLP layer-1 weights early (hide L2 latency under gates) ----
  const int j32 = lane & 31, k16 = lane & 15;
  float w1r[10];
  #pragma unroll
  for (int i = 0; i < NQ; ++i) w1r[i] = W1[i * 32 + j32];
  float b1v = b1[j32], b2v = b2[k16], w3v = W3[k16], b3v = b3[0];

  // ---- 30 Rot matrices lane-parallel (lane g -> gate g), no prep kernel ----
  Umat m;
  {
    int g = (lane < 30) ? lane : 0;
    float wa = wts[g * 3 + 0], wb = wts[g * 3 + 1], wc = wts[g * 3 + 2];
    float al = 0.5f * (wa + wc), be = 0.5f * (wa - wc), hb = 0.5f * wb;
    float ca = __cosf(al),  sa = __sinf(al);
    float cbe = __cosf(be), sbe = __sinf(be);
    float cb = __cosf(hb),  sb = __sinf(hb);
    m.r00 =  cb * ca;  m.i00 = -cb * sa;
    m.r01 = -sb * cbe; m.i01 = -sb * sbe;
    m.r10 =  sb * cbe; m.i10 = -sb * sbe;
    m.r11 =  cb * ca;  m.i11 =  cb * sa;
  }

  cplx u00, u01, u10, u11;
  const float* zp = z + wv * NQ;           // wave-uniform -> scalar loads

  // ---- init: RY product state fused with layer-0 1q gates (identity layout) ----
  cplx laneF = {1.f, 0.f};
  #pragma unroll
  for (int q = 0; q < 6; ++q) {            // wires 0..5 -> lane bits 5..0
    float zz = fminf(fmaxf(zp[q], -1.f), 1.f);
    float c0 = __cosf(0.5f * zz), s0 = __sinf(0.5f * zz);
    getU(m, q, u00, u01, u10, u11);
    cplx va = { fmaf(u00.re, c0, u01.re * s0), fmaf(u00.im, c0, u01.im * s0) };
    cplx vb = { fmaf(u10.re, c0, u11.re * s0), fmaf(u10.im, c0, u11.im * s0) };
    cplx f = csel((lane >> (5 - q)) & 1, vb, va);
    laneF = (q == 0) ? f : cmul(laneF, f);
  }
  cplx va_[4], vb_[4];                     // wires 6..9 -> local bits 3..0
  #pragma unroll
  for (int q = 6; q < 10; ++q) {
    float zz = fminf(fmaxf(zp[q], -1.f), 1.f);
    float c0 = __cosf(0.5f * zz), s0 = __sinf(0.5f * zz);
    getU(m, q, u00, u01, u10, u11);
    va_[q - 6] = { fmaf(u00.re, c0, u01.re * s0), fmaf(u00.im, c0, u01.im * s0) };
    vb_[q - 6] = { fmaf(u10.re, c0, u11.re * s0), fmaf(u10.im, c0, u11.im * s0) };
  }

  cplx amp[16];
  {
    cplx P2[4];
    P2[0] = cmul(va_[2], va_[3]);
    P2[1] = cmul(va_[2], vb_[3]);
    P2[2] = cmul(vb_[2], va_[3]);
    P2[3] = cmul(vb_[2], vb_[3]);
    cplx g0 = cmul(laneF, va_[0]);         // wire6 = bit3
    cplx g1 = cmul(laneF, vb_[0]);
    #pragma unroll
    for (int t = 0; t < 16; ++t) {
      cplx t7 = ((t >> 2) & 1) ? vb_[1] : va_[1];
      cplx tt = cmul(t7, P2[t & 3]);
      amp[t] = cmul(((t >> 3) & 1) ? g1 : g0, tt);
    }
  }

  // ---- Layer 1 under layout C^1 ----
  getU(m, 10, u00,u01,u10,u11); gate_shfl <0x30, 0x20>(amp, lane, u00,u01,u10,u11);        // b=9
  getU(m, 11, u00,u01,u10,u11); gate_swz  <0x601F, 0x30>(amp, lane, u00,u01,u10,u11);      // b=8 xor 0x18
  getU(m, 12, u00,u01,u10,u11); gate_dpp2 <0x140, 0x1B, 0x38>(amp, lane, u00,u01,u10,u11); // b=7 xorC
  getU(m, 13, u00,u01,u10,u11); gate_dpp2 <0x141, 0xB1, 0x3C>(amp, lane, u00,u01,u10,u11); // b=6 xor6
  getU(m, 14, u00,u01,u10,u11); gate_dpp1 <0x1B, 0x3E>(amp, lane, u00,u01,u10,u11);        // b=5 xor3
  getU(m, 15, u00,u01,u10,u11); gate_mixed<0xB1, 8, 0x3F>(amp, lane, u00,u01,u10,u11);     // b=4
  getU(m, 16, u00,u01,u10,u11); gate_local<0xC, 0x3F, 0x8>(amp, lane, u00,u01,u10,u11);    // b=3
  getU(m, 17, u00,u01,u10,u11); gate_local<0x6, 0x3F, 0xC>(amp, lane, u00,u01,u10,u11);    // b=2
  getU(m, 18, u00,u01,u10,u11); gate_local<0x3, 0x3F, 0xE>(amp, lane, u00,u01,u10,u11);    // b=1
  getU(m, 19, u00,u01,u10,u11); gate_local<0x1, 0x3F, 0xF>(amp, lane, u00,u01,u10,u11);    // b=0

  // ---- Layer 2 under layout C^2 ----
  getU(m, 20, u00,u01,u10,u11); gate_shfl <0x28, 0x20>(amp, lane, u00,u01,u10,u11);        // b=9
  getU(m, 21, u00,u01,u10,u11); gate_swz  <0x501F, 0x10>(amp, lane, u00,u01,u10,u11);      // b=8 xor 0x14
  getU(m, 22, u00,u01,u10,u11); gate_dpp2 <0x128, 0x4E, 0x28>(amp, lane, u00,u01,u10,u11); // b=7 xorA
  getU(m, 23, u00,u01,u10,u11); gate_dpp2 <0x141, 0x4E, 0x14>(amp, lane, u00,u01,u10,u11); // b=6 xor5
  getU(m, 24, u00,u01,u10,u11); gate_mixed<0x4E, 8, 0x2A>(amp, lane, u00,u01,u10,u11);     // b=5
  getU(m, 25, u00,u01,u10,u11); gate_mixed<0xB1, 4, 0x15>(amp, lane, u00,u01,u10,u11);     // b=4
  getU(m, 26, u00,u01,u10,u11); gate_local<0xA, 0x2A, 0x8>(amp, lane, u00,u01,u10,u11);    // b=3
  getU(m, 27, u00,u01,u10,u11); gate_local<0x5, 0x15, 0x4>(amp, lane, u00,u01,u10,u11);    // b=2
  getU(m, 28, u00,u01,u10,u11); gate_local<0x2, 0x2A, 0xA>(amp, lane, u00,u01,u10,u11);    // b=1
  getU(m, 29, u00,u01,u10,u11); gate_local<0x1, 0x15, 0x5>(amp, lane, u00,u01,u10,u11);    // b=0

  // ---- prefetch W2 (consumed ~300 instrs later) ----
  float w2r[32];
  #pragma unroll
  for (int jj = 0; jj < 32; ++jj) w2r[jj] = W2[jj * 16 + k16];

  // ---- measurement under layout C^3 via Walsh-Hadamard transform ----
  float p[16];
  #pragma unroll
  for (int t = 0; t < 16; ++t)
    p[t] = fmaf(amp[t].re, amp[t].re, amp[t].im * amp[t].im);

  // local 4-bit WHT: p[m] := sum_t p0[t] (-1)^popc(t&m)
  #pragma unroll
  for (int k = 1; k <= 8; k <<= 1) {
    #pragma unroll
    for (int t = 0; t < 16; ++t) {
      if (t & k) continue;
      float a = p[t], b = p[t | k];
      p[t] = a + b; p[t | k] = a - b;
    }
  }

  // lane-space butterflies (sign floats shared across all 5 sources)
  float s1  = (lane & 1)  ? -1.f : 1.f;
  float s2  = (lane & 2)  ? -1.f : 1.f;
  float s4  = (lane & 4)  ? -1.f : 1.f;
  float s8  = (lane & 8)  ? -1.f : 1.f;
  float s16 = (lane & 16) ? -1.f : 1.f;
  float s32 = (lane & 32) ? -1.f : 1.f;
  float B0 = wht6(p[0],   s1,s2,s4,s8,s16,s32);
  float B8 = wht6(p[8],   s1,s2,s4,s8,s16,s32);
  float BC = wht6(p[0xC], s1,s2,s4,s8,s16,s32);
  float B6 = wht6(p[6],   s1,s2,s4,s8,s16,s32);
  float B3 = wht6(p[3],   s1,s2,s4,s8,s16,s32);

  // feats[w] = WHT point at (lane mask | local mask) -- all wave-uniform SGPRs
  float f0 = rdlane(B0, 0x20), f1 = rdlane(B0, 0x30);
  float f2 = rdlane(B0, 0x18), f3 = rdlane(B0, 0x0C);
  float f4 = rdlane(B0, 0x26), f5 = rdlane(B0, 0x33);
  float f6 = rdlane(B8, 0x19), f7 = rdlane(BC, 0x0C);
  float f8 = rdlane(B6, 0x26), f9 = rdlane(B3, 0x33);
  float feats[10] = {f0,f1,f2,f3,f4,f5,f6,f7,f8,f9};

  // ---- MLP: 10->32 tanh ->16 tanh ->1 ; sigmoid*0.2-0.1 == 0.1*tanh(raw/2) ----
  float acc = b1v;
  #pragma unroll
  for (int i = 0; i < NQ; ++i) acc = fmaf(feats[i], w1r[i], acc);
  float h1 = fast_tanh(acc);

  float acc2 = b2v;
  #pragma unroll
  for (int jj = 0; jj < 32; ++jj)
    acc2 = fmaf(rdlane(h1, jj), w2r[jj], acc2);     // readlane: 0 DS
  float h2 = fast_tanh(acc2);

  float vv = h2 * w3v;
  vv += dppf<0xB1>(vv);
  vv += dppf<0x4E>(vv);
  vv += dppf<0x1B>(dppf<0x141>(vv));   // xor4 via DPP chain
  vv += dppf<0x128>(vv);

  if (lane == 0) out[wv] = 0.1f * fast_tanh(0.5f * (vv + b3v));
}

} // namespace

extern "C" void kernel_launch(void* const* d_in, const int* in_sizes, int n_in,
                              void* d_out, int out_size, void* d_ws, size_t ws_size,
                              hipStream_t stream) {
  const float* z   = (const float*)d_in[0];
  const float* wts = (const float*)d_in[1];
  const float* W1  = (const float*)d_in[2];
  const float* b1  = (const float*)d_in[3];
  const float* W2  = (const float*)d_in[4];
  const float* b2  = (const float*)d_in[5];
  const float* W3  = (const float*)d_in[6];
  const float* b3  = (const float*)d_in[7];
  float* out = (float*)d_out;
  (void)d_ws; (void)ws_size;

  int B = in_sizes[0] / NQ;                 // 4096
  int blocks = (B + 3) / 4;                 // 4 waves (elements) per 256-thread block
  hipLaunchKernelGGL(qgan_kernel, dim3(blocks), dim3(256), 0, stream,
                     z, wts, W1, b1, W2, b2, W3, b3, out, B);
}

// Round 5
// 92.580 us; speedup vs baseline: 1.0311x; 1.0311x over previous
//
#include <hip/hip_runtime.h>

namespace {

constexpr int NQ = 10;

struct cplx { float re, im; };

__device__ __forceinline__ cplx cmul(cplx a, cplx b) {
  return cplx{ fmaf(a.re, b.re, -a.im * b.im), fmaf(a.re, b.im, a.im * b.re) };
}
// u*a + v*b (complex), 8 scalar FMA
__device__ __forceinline__ cplx cmadd2(cplx u, cplx a, cplx v, cplx b) {
  cplx r;
  r.re = fmaf(u.re, a.re, fmaf(-u.im, a.im, fmaf(v.re, b.re, -v.im * b.im)));
  r.im = fmaf(u.re, a.im, fmaf( u.im, a.re, fmaf(v.re, b.im,  v.im * b.re)));
  return r;
}
__device__ __forceinline__ cplx csel(bool c, cplx x, cplx y) {
  return cplx{ c ? x.re : y.re, c ? x.im : y.im };
}

__device__ __forceinline__ float fast_tanh(float x) {
  float xc = fminf(fmaxf(x, -10.f), 10.f);
  float e = __expf(2.f * xc);
  return __fdividef(e - 1.f, e + 1.f);
}

// ---- cross-lane primitives ----
__device__ __forceinline__ float rdlane(float v, int l) {
  return __int_as_float(__builtin_amdgcn_readlane(__float_as_int(v), l));
}
// DPP: quad_perm xor1=0xB1 xor2=0x4E xor3=0x1B; row_ror:8=0x128 (xor8);
// row_half_mirror=0x141 (xor7)
template<int CTRL>
__device__ __forceinline__ float dppf(float v) {
  return __int_as_float(__builtin_amdgcn_update_dpp(0, __float_as_int(v), CTRL, 0xF, 0xF, true));
}
template<int CTRL>
__device__ __forceinline__ cplx dppc(cplx v) { return cplx{ dppf<CTRL>(v.re), dppf<CTRL>(v.im) }; }

template<int PAT>   // ds_swizzle BitMode: (xor<<10)|(or<<5)|and
__device__ __forceinline__ float swzf(float v) {
  return __int_as_float(__builtin_amdgcn_ds_swizzle(__float_as_int(v), PAT));
}
__device__ __forceinline__ float bperm(int addr, float v) {
  return __int_as_float(__builtin_amdgcn_ds_bpermute(addr, __float_as_int(v)));
}

// ---- per-lane Rot matrices (lane g holds gate g), broadcast by readlane ----
struct Umat { float r00,i00,r01,i01,r10,i10,r11,i11; };
__device__ __forceinline__ void getU(const Umat& m, int g,
                                     cplx& u00, cplx& u01, cplx& u10, cplx& u11) {
  u00 = cplx{rdlane(m.r00, g), rdlane(m.i00, g)};
  u01 = cplx{rdlane(m.r01, g), rdlane(m.i01, g)};
  u10 = cplx{rdlane(m.r10, g), rdlane(m.i10, g)};
  u11 = cplx{rdlane(m.r11, g), rdlane(m.i11, g)};
}

// ---- lane-pure gate, runtime masks, BATCHED gather (issue all 32 DS, then consume) ----
__device__ __forceinline__ void gate_lane_rt(cplx (&amp)[16], int lane, const Umat& m,
                                             int g, int LX, int HIL) {
  cplx u00, u01, u10, u11; getU(m, g, u00, u01, u10, u11);
  bool hi = (__popc(lane & HIL) & 1) != 0;
  cplx cA = csel(hi, u11, u00), cB = csel(hi, u10, u01);
  const int addr = (lane ^ LX) << 2;
  float ore[16], oim[16];
  #pragma unroll
  for (int t = 0; t < 16; ++t) { ore[t] = bperm(addr, amp[t].re); oim[t] = bperm(addr, amp[t].im); }
  #pragma unroll
  for (int t = 0; t < 16; ++t) amp[t] = cmadd2(cA, amp[t], cB, cplx{ore[t], oim[t]});
}

// Mixed gate: partner = (lane ^ dpp-xor, t ^ LOCX); hi = parity(lane&HIL). Pure VALU.
template<int CTRL, int LOCX, int HIL>
__device__ __forceinline__ void gate_mixed(cplx (&amp)[16], int lane, cplx u00,cplx u01,cplx u10,cplx u11) {
  bool hi = (__popc(lane & HIL) & 1) != 0;
  cplx cA = csel(hi, u11, u00), cB = csel(hi, u10, u01);
  #pragma unroll
  for (int t0 = 0; t0 < 16; ++t0) {
    if (t0 & LOCX) continue;
    const int t1 = t0 | LOCX;
    cplx o0 = dppc<CTRL>(amp[t1]);
    cplx o1 = dppc<CTRL>(amp[t0]);
    amp[t0] = cmadd2(cA, amp[t0], cB, o0);
    amp[t1] = cmadd2(cA, amp[t1], cB, o1);
  }
}
constexpr int hbit(int m) { return m >= 8 ? 8 : (m >= 4 ? 4 : (m >= 2 ? 2 : 1)); }
// Pure local gate: pair = t ^ PLOC; hi = parity(lane&HIL) ^ parity(t&HILOC). Pure VALU.
template<int PLOC, int HIL, int HILOC>
__device__ __forceinline__ void gate_local(cplx (&amp)[16], int lane, cplx u00,cplx u01,cplx u10,cplx u11) {
  bool h0 = (__popc(lane & HIL) & 1) != 0;
  cplx cA0 = csel(h0, u11, u00), cB0 = csel(h0, u10, u01);
  cplx cA1 = csel(h0, u00, u11), cB1 = csel(h0, u01, u10);
  #pragma unroll
  for (int ta = 0; ta < 16; ++ta) {
    if (ta & hbit(PLOC)) continue;
    const int tb = ta ^ PLOC;
    const bool pa = (__popc(ta & HILOC) & 1) != 0;   // compile-time
    cplx aA = amp[ta], aB = amp[tb];
    if (!pa) { amp[ta] = cmadd2(cA0, aA, cB0, aB); amp[tb] = cmadd2(cA1, aB, cB1, aA); }
    else     { amp[ta] = cmadd2(cA1, aA, cB1, aB); amp[tb] = cmadd2(cA0, aB, cB0, aA); }
  }
}

// 6-stage lane-space Walsh-Hadamard butterfly: lane m ends with sum_l v(l)*(-1)^popc(l&m)
__device__ __forceinline__ float wht6(float v, float s1, float s2, float s4,
                                      float s8, float s16, float s32) {
  float o;
  o = dppf<0xB1>(v);               v = fmaf(s1,  v, o);   // xor1
  o = dppf<0x4E>(v);               v = fmaf(s2,  v, o);   // xor2
  o = dppf<0x1B>(dppf<0x141>(v));  v = fmaf(s4,  v, o);   // xor4 = xor7 o xor3
  o = dppf<0x128>(v);              v = fmaf(s8,  v, o);   // xor8
  o = swzf<0x401F>(v);             v = fmaf(s16, v, o);   // xor16 (DS swizzle)
  o = __shfl_xor(v, 32);           v = fmaf(s32, v, o);   // xor32 (DS bpermute)
  return v;
}

// packed mask tables: 6 bits per gate
constexpr int pk6(int a, int b, int c, int d, int e) {
  return a | (b << 6) | (c << 12) | (d << 18) | (e << 24);
}
constexpr int LX1  = pk6(0x30, 0x18, 0x0C, 0x06, 0x03);
constexpr int HIL1 = pk6(0x20, 0x30, 0x38, 0x3C, 0x3E);
constexpr int LX2  = pk6(0x28, 0x14, 0x0A, 0x05, 0);
constexpr int HIL2 = pk6(0x20, 0x10, 0x28, 0x14, 0);

__global__ __launch_bounds__(64, 4)
void qgan_kernel(const float* __restrict__ z, const float* __restrict__ wts,
                 const float* __restrict__ W1, const float* __restrict__ b1,
                 const float* __restrict__ W2, const float* __restrict__ b2,
                 const float* __restrict__ W3, const float* __restrict__ b3,
                 float* __restrict__ out, int B)
{
  const int lane = threadIdx.x;            // one batch element per wave/block
  const int wv   = blockIdx.x;
  if (wv >= B) return;

  // ---- prefetch MLP layer-1 weights early (hide L2 latency under gates) ----
  const int j32 = lane & 31, k16 = lane & 15;
  float w1r[10];
  #pragma unroll
  for (int i = 0; i < NQ; ++i) w1r[i] = W1[i * 32 + j32];
  float b1v = b1[j32], b2v = b2[k16], w3v = W3[k16], b3v = b3[0];

  // ---- 30 Rot matrices lane-parallel (lane g -> gate g) ----
  Umat m;
  {
    int g = (lane < 30) ? lane : 0;
    float wa = wts[g * 3 + 0], wb = wts[g * 3 + 1], wc = wts[g * 3 + 2];
    float al = 0.5f * (wa + wc), be = 0.5f * (wa - wc), hb = 0.5f * wb;
    float ca = __cosf(al),  sa = __sinf(al);
    float cbe = __cosf(be), sbe = __sinf(be);
    float cb = __cosf(hb),  sb = __sinf(hb);
    m.r00 =  cb * ca;  m.i00 = -cb * sa;
    m.r01 = -sb * cbe; m.i01 = -sb * sbe;
    m.r10 =  sb * cbe; m.i10 = -sb * sbe;
    m.r11 =  cb * ca;  m.i11 =  cb * sa;
  }

  cplx u00, u01, u10, u11;
  const float* zp = z + wv * NQ;           // wave-uniform -> scalar loads

  // ---- init: RY product state fused with layer-0 1q gates (identity layout) ----
  cplx laneF = {1.f, 0.f};
  #pragma unroll
  for (int q = 0; q < 6; ++q) {            // wires 0..5 -> lane bits 5..0
    float zz = fminf(fmaxf(zp[q], -1.f), 1.f);
    float c0 = __cosf(0.5f * zz), s0 = __sinf(0.5f * zz);
    getU(m, q, u00, u01, u10, u11);
    cplx va = { fmaf(u00.re, c0, u01.re * s0), fmaf(u00.im, c0, u01.im * s0) };
    cplx vb = { fmaf(u10.re, c0, u11.re * s0), fmaf(u10.im, c0, u11.im * s0) };
    cplx f = csel((lane >> (5 - q)) & 1, vb, va);
    laneF = (q == 0) ? f : cmul(laneF, f);
  }
  cplx va_[4], vb_[4];                     // wires 6..9 -> local bits 3..0
  #pragma unroll
  for (int q = 6; q < 10; ++q) {
    float zz = fminf(fmaxf(zp[q], -1.f), 1.f);
    float c0 = __cosf(0.5f * zz), s0 = __sinf(0.5f * zz);
    getU(m, q, u00, u01, u10, u11);
    va_[q - 6] = { fmaf(u00.re, c0, u01.re * s0), fmaf(u00.im, c0, u01.im * s0) };
    vb_[q - 6] = { fmaf(u10.re, c0, u11.re * s0), fmaf(u10.im, c0, u11.im * s0) };
  }

  cplx amp[16];
  {
    cplx P2[4];
    P2[0] = cmul(va_[2], va_[3]);
    P2[1] = cmul(va_[2], vb_[3]);
    P2[2] = cmul(vb_[2], va_[3]);
    P2[3] = cmul(vb_[2], vb_[3]);
    cplx g0 = cmul(laneF, va_[0]);         // wire6 = bit3
    cplx g1 = cmul(laneF, vb_[0]);
    #pragma unroll
    for (int t = 0; t < 16; ++t) {
      cplx t7 = ((t >> 2) & 1) ? vb_[1] : va_[1];
      cplx tt = cmul(t7, P2[t & 3]);
      amp[t] = cmul(((t >> 3) & 1) ? g1 : g0, tt);
    }
  }

  // ---- Layer 1 under layout C^1 (CNOT chains algebraically folded) ----
  #pragma unroll 1
  for (int i = 0; i < 5; ++i)              // b = 9..5, rolled, batched DS
    gate_lane_rt(amp, lane, m, 10 + i, (LX1 >> (6 * i)) & 63, (HIL1 >> (6 * i)) & 63);
  getU(m, 15, u00,u01,u10,u11); gate_mixed<0xB1, 8, 0x3F>(amp, lane, u00,u01,u10,u11);   // b=4
  getU(m, 16, u00,u01,u10,u11); gate_local<0xC, 0x3F, 0x8>(amp, lane, u00,u01,u10,u11);  // b=3
  getU(m, 17, u00,u01,u10,u11); gate_local<0x6, 0x3F, 0xC>(amp, lane, u00,u01,u10,u11);  // b=2
  getU(m, 18, u00,u01,u10,u11); gate_local<0x3, 0x3F, 0xE>(amp, lane, u00,u01,u10,u11);  // b=1
  getU(m, 19, u00,u01,u10,u11); gate_local<0x1, 0x3F, 0xF>(amp, lane, u00,u01,u10,u11);  // b=0

  // ---- Layer 2 under layout C^2 ----
  #pragma unroll 1
  for (int i = 0; i < 4; ++i)              // b = 9..6, rolled, batched DS
    gate_lane_rt(amp, lane, m, 20 + i, (LX2 >> (6 * i)) & 63, (HIL2 >> (6 * i)) & 63);
  getU(m, 24, u00,u01,u10,u11); gate_mixed<0x4E, 8, 0x2A>(amp, lane, u00,u01,u10,u11);   // b=5
  getU(m, 25, u00,u01,u10,u11); gate_mixed<0xB1, 4, 0x15>(amp, lane, u00,u01,u10,u11);   // b=4
  getU(m, 26, u00,u01,u10,u11); gate_local<0xA, 0x2A, 0x8>(amp, lane, u00,u01,u10,u11);  // b=3
  getU(m, 27, u00,u01,u10,u11); gate_local<0x5, 0x15, 0x4>(amp, lane, u00,u01,u10,u11);  // b=2
  getU(m, 28, u00,u01,u10,u11); gate_local<0x2, 0x2A, 0xA>(amp, lane, u00,u01,u10,u11);  // b=1
  getU(m, 29, u00,u01,u10,u11); gate_local<0x1, 0x15, 0x5>(amp, lane, u00,u01,u10,u11);  // b=0

  // ---- prefetch W2 (consumed after WHT) ----
  float w2r[32];
  #pragma unroll
  for (int jj = 0; jj < 32; ++jj) w2r[jj] = W2[jj * 16 + k16];

  // ---- measurement under layout C^3 via Walsh-Hadamard transform ----
  float p[16];
  #pragma unroll
  for (int t = 0; t < 16; ++t)
    p[t] = fmaf(amp[t].re, amp[t].re, amp[t].im * amp[t].im);

  // local 4-bit WHT: p[m] := sum_t p0[t] (-1)^popc(t&m)
  #pragma unroll
  for (int k = 1; k <= 8; k <<= 1) {
    #pragma unroll
    for (int t = 0; t < 16; ++t) {
      if (t & k) continue;
      float a = p[t], b = p[t | k];
      p[t] = a + b; p[t | k] = a - b;
    }
  }

  float s1  = (lane & 1)  ? -1.f : 1.f;
  float s2  = (lane & 2)  ? -1.f : 1.f;
  float s4  = (lane & 4)  ? -1.f : 1.f;
  float s8  = (lane & 8)  ? -1.f : 1.f;
  float s16 = (lane & 16) ? -1.f : 1.f;
  float s32 = (lane & 32) ? -1.f : 1.f;
  float B0 = wht6(p[0],   s1,s2,s4,s8,s16,s32);
  float B8 = wht6(p[8],   s1,s2,s4,s8,s16,s32);
  float BC = wht6(p[0xC], s1,s2,s4,s8,s16,s32);
  float B6 = wht6(p[6],   s1,s2,s4,s8,s16,s32);
  float B3 = wht6(p[3],   s1,s2,s4,s8,s16,s32);

  // feats[w] = WHT point at (lane mask | local mask) -- wave-uniform SGPRs
  float feats[10];
  feats[0] = rdlane(B0, 0x20); feats[1] = rdlane(B0, 0x30);
  feats[2] = rdlane(B0, 0x18); feats[3] = rdlane(B0, 0x0C);
  feats[4] = rdlane(B0, 0x26); feats[5] = rdlane(B0, 0x33);
  feats[6] = rdlane(B8, 0x19); feats[7] = rdlane(BC, 0x0C);
  feats[8] = rdlane(B6, 0x26); feats[9] = rdlane(B3, 0x33);

  // ---- MLP: 10->32 tanh ->16 tanh ->1 ; sigmoid*0.2-0.1 == 0.1*tanh(raw/2) ----
  float acc = b1v;
  #pragma unroll
  for (int i = 0; i < NQ; ++i) acc = fmaf(feats[i], w1r[i], acc);
  float h1 = fast_tanh(acc);

  float acc2 = b2v;
  #pragma unroll
  for (int jj = 0; jj < 32; ++jj)
    acc2 = fmaf(rdlane(h1, jj), w2r[jj], acc2);     // readlane: 0 DS
  float h2 = fast_tanh(acc2);

  float vv = h2 * w3v;
  vv += dppf<0xB1>(vv);
  vv += dppf<0x4E>(vv);
  vv += dppf<0x1B>(dppf<0x141>(vv));   // xor4 via DPP chain
  vv += dppf<0x128>(vv);

  if (lane == 0) out[wv] = 0.1f * fast_tanh(0.5f * (vv + b3v));
}

} // namespace

extern "C" void kernel_launch(void* const* d_in, const int* in_sizes, int n_in,
                              void* d_out, int out_size, void* d_ws, size_t ws_size,
                              hipStream_t stream) {
  const float* z   = (const float*)d_in[0];
  const float* wts = (const float*)d_in[1];
  const float* W1  = (const float*)d_in[2];
  const float* b1  = (const float*)d_in[3];
  const float* W2  = (const float*)d_in[4];
  const float* b2  = (const float*)d_in[5];
  const float* W3  = (const float*)d_in[6];
  const float* b3  = (const float*)d_in[7];
  float* out = (float*)d_out;
  (void)d_ws; (void)ws_size;

  int B = in_sizes[0] / NQ;                 // 4096
  hipLaunchKernelGGL(qgan_kernel, dim3(B), dim3(64), 0, stream,
                     z, wts, W1, b1, W2, b2, W3, b3, out, B);
}

// Round 6
// 90.939 us; speedup vs baseline: 1.0497x; 1.0180x over previous
//
#include <hip/hip_runtime.h>

namespace {

constexpr int NQ = 10;

struct cplx { float re, im; };

__device__ __forceinline__ cplx cmul(cplx a, cplx b) {
  return cplx{ fmaf(a.re, b.re, -a.im * b.im), fmaf(a.re, b.im, a.im * b.re) };
}
// u*a + v*b (complex), 8 scalar FMA
__device__ __forceinline__ cplx cmadd2(cplx u, cplx a, cplx v, cplx b) {
  cplx r;
  r.re = fmaf(u.re, a.re, fmaf(-u.im, a.im, fmaf(v.re, b.re, -v.im * b.im)));
  r.im = fmaf(u.re, a.im, fmaf( u.im, a.re, fmaf(v.re, b.im,  v.im * b.re)));
  return r;
}
__device__ __forceinline__ cplx csel(bool c, cplx x, cplx y) {
  return cplx{ c ? x.re : y.re, c ? x.im : y.im };
}

__device__ __forceinline__ float fast_tanh(float x) {
  float xc = fminf(fmaxf(x, -10.f), 10.f);
  float e = __expf(2.f * xc);
  return __fdividef(e - 1.f, e + 1.f);
}

// ---- cross-lane primitives ----
__device__ __forceinline__ float rdlane(float v, int l) {
  return __int_as_float(__builtin_amdgcn_readlane(__float_as_int(v), l));
}
// DPP: quad_perm xor1=0xB1 xor2=0x4E xor3=0x1B; row_ror:8=0x128 (xor8);
// row_half_mirror=0x141 (xor7)
template<int CTRL>
__device__ __forceinline__ float dppf(float v) {
  return __int_as_float(__builtin_amdgcn_update_dpp(0, __float_as_int(v), CTRL, 0xF, 0xF, true));
}
template<int CTRL>
__device__ __forceinline__ cplx dppc(cplx v) { return cplx{ dppf<CTRL>(v.re), dppf<CTRL>(v.im) }; }

template<int PAT>   // ds_swizzle BitMode: (xor<<10)|(or<<5)|and
__device__ __forceinline__ float swzf(float v) {
  return __int_as_float(__builtin_amdgcn_ds_swizzle(__float_as_int(v), PAT));
}
__device__ __forceinline__ float bperm(int addr, float v) {
  return __int_as_float(__builtin_amdgcn_ds_bpermute(addr, __float_as_int(v)));
}

// ---- per-lane Rot matrices (lane g holds gate g), broadcast by readlane ----
struct Umat { float r00,i00,r01,i01,r10,i10,r11,i11; };
__device__ __forceinline__ void getU(const Umat& m, int g,
                                     cplx& u00, cplx& u01, cplx& u10, cplx& u11) {
  u00 = cplx{rdlane(m.r00, g), rdlane(m.i00, g)};
  u01 = cplx{rdlane(m.r01, g), rdlane(m.i01, g)};
  u10 = cplx{rdlane(m.r10, g), rdlane(m.i10, g)};
  u11 = cplx{rdlane(m.r11, g), rdlane(m.i11, g)};
}

// ---- lane-pure gate, runtime masks, BATCHED gather (issue all 32 DS, then consume) ----
__device__ __forceinline__ void gate_lane_rt(cplx (&amp)[16], int lane, const Umat& m,
                                             int g, int LX, int HIL) {
  cplx u00, u01, u10, u11; getU(m, g, u00, u01, u10, u11);
  bool hi = (__popc(lane & HIL) & 1) != 0;
  cplx cA = csel(hi, u11, u00), cB = csel(hi, u10, u01);
  const int addr = (lane ^ LX) << 2;
  float ore[16], oim[16];
  #pragma unroll
  for (int t = 0; t < 16; ++t) { ore[t] = bperm(addr, amp[t].re); oim[t] = bperm(addr, amp[t].im); }
  #pragma unroll
  for (int t = 0; t < 16; ++t) amp[t] = cmadd2(cA, amp[t], cB, cplx{ore[t], oim[t]});
}

// Mixed gate: partner = (lane ^ dpp-xor, t ^ LOCX); hi = parity(lane&HIL). Pure VALU.
template<int CTRL, int LOCX, int HIL>
__device__ __forceinline__ void gate_mixed(cplx (&amp)[16], int lane, cplx u00,cplx u01,cplx u10,cplx u11) {
  bool hi = (__popc(lane & HIL) & 1) != 0;
  cplx cA = csel(hi, u11, u00), cB = csel(hi, u10, u01);
  #pragma unroll
  for (int t0 = 0; t0 < 16; ++t0) {
    if (t0 & LOCX) continue;
    const int t1 = t0 | LOCX;
    cplx o0 = dppc<CTRL>(amp[t1]);
    cplx o1 = dppc<CTRL>(amp[t0]);
    amp[t0] = cmadd2(cA, amp[t0], cB, o0);
    amp[t1] = cmadd2(cA, amp[t1], cB, o1);
  }
}
constexpr int hbit(int m) { return m >= 8 ? 8 : (m >= 4 ? 4 : (m >= 2 ? 2 : 1)); }
// Pure local gate: pair = t ^ PLOC; hi = parity(lane&HIL) ^ parity(t&HILOC). Pure VALU.
template<int PLOC, int HIL, int HILOC>
__device__ __forceinline__ void gate_local(cplx (&amp)[16], int lane, cplx u00,cplx u01,cplx u10,cplx u11) {
  bool h0 = (__popc(lane & HIL) & 1) != 0;
  cplx cA0 = csel(h0, u11, u00), cB0 = csel(h0, u10, u01);
  cplx cA1 = csel(h0, u00, u11), cB1 = csel(h0, u01, u10);
  #pragma unroll
  for (int ta = 0; ta < 16; ++ta) {
    if (ta & hbit(PLOC)) continue;
    const int tb = ta ^ PLOC;
    const bool pa = (__popc(ta & HILOC) & 1) != 0;   // compile-time
    cplx aA = amp[ta], aB = amp[tb];
    if (!pa) { amp[ta] = cmadd2(cA0, aA, cB0, aB); amp[tb] = cmadd2(cA1, aB, cB1, aA); }
    else     { amp[ta] = cmadd2(cA1, aA, cB1, aB); amp[tb] = cmadd2(cA0, aB, cB0, aA); }
  }
}

// 6-stage lane-space Walsh-Hadamard butterfly: lane m ends with sum_l v(l)*(-1)^popc(l&m)
__device__ __forceinline__ float wht6(float v, float s1, float s2, float s4,
                                      float s8, float s16, float s32) {
  float o;
  o = dppf<0xB1>(v);               v = fmaf(s1,  v, o);   // xor1
  o = dppf<0x4E>(v);               v = fmaf(s2,  v, o);   // xor2
  o = dppf<0x1B>(dppf<0x141>(v));  v = fmaf(s4,  v, o);   // xor4 = xor7 o xor3
  o = dppf<0x128>(v);              v = fmaf(s8,  v, o);   // xor8
  o = swzf<0x401F>(v);             v = fmaf(s16, v, o);   // xor16 (DS swizzle)
  o = __shfl_xor(v, 32);           v = fmaf(s32, v, o);   // xor32 (DS bpermute)
  return v;
}

// packed mask tables: 6 bits per gate
constexpr int pk6(int a, int b, int c, int d, int e) {
  return a | (b << 6) | (c << 12) | (d << 18) | (e << 24);
}
constexpr int LX1  = pk6(0x30, 0x18, 0x0C, 0x06, 0x03);
constexpr int HIL1 = pk6(0x20, 0x30, 0x38, 0x3C, 0x3E);
constexpr int LX2  = pk6(0x28, 0x14, 0x0A, 0x05, 0);
constexpr int HIL2 = pk6(0x20, 0x10, 0x28, 0x14, 0);

// launch_bounds (64, 1): 64-thread block = 1 wave; min 1 wave/EU under BOTH
// readings of the 2nd arg -> VGPR cap 512. Previous rounds' (.,4) capped the
// allocator at 128 (or 32) VGPRs -> amp[]/coeff live-set spilled to scratch.
__global__ __launch_bounds__(64, 1)
void qgan_kernel(const float* __restrict__ z, const float* __restrict__ wts,
                 const float* __restrict__ W1, const float* __restrict__ b1,
                 const float* __restrict__ W2, const float* __restrict__ b2,
                 const float* __restrict__ W3, const float* __restrict__ b3,
                 float* __restrict__ out, int B)
{
  const int lane = threadIdx.x;            // one batch element per wave/block
  const int wv   = blockIdx.x;
  if (wv >= B) return;

  // ---- prefetch MLP layer-1 weights early (hide L2 latency under gates) ----
  const int j32 = lane & 31, k16 = lane & 15;
  float w1r[10];
  #pragma unroll
  for (int i = 0; i < NQ; ++i) w1r[i] = W1[i * 32 + j32];
  float b1v = b1[j32], b2v = b2[k16], w3v = W3[k16], b3v = b3[0];

  // ---- 30 Rot matrices lane-parallel (lane g -> gate g) ----
  Umat m;
  {
    int g = (lane < 30) ? lane : 0;
    float wa = wts[g * 3 + 0], wb = wts[g * 3 + 1], wc = wts[g * 3 + 2];
    float al = 0.5f * (wa + wc), be = 0.5f * (wa - wc), hb = 0.5f * wb;
    float ca = __cosf(al),  sa = __sinf(al);
    float cbe = __cosf(be), sbe = __sinf(be);
    float cb = __cosf(hb),  sb = __sinf(hb);
    m.r00 =  cb * ca;  m.i00 = -cb * sa;
    m.r01 = -sb * cbe; m.i01 = -sb * sbe;
    m.r10 =  sb * cbe; m.i10 = -sb * sbe;
    m.r11 =  cb * ca;  m.i11 =  cb * sa;
  }

  cplx u00, u01, u10, u11;
  const float* zp = z + wv * NQ;           // wave-uniform -> scalar loads

  // ---- init: RY product state fused with layer-0 1q gates (identity layout) ----
  cplx laneF = {1.f, 0.f};
  #pragma unroll
  for (int q = 0; q < 6; ++q) {            // wires 0..5 -> lane bits 5..0
    float zz = fminf(fmaxf(zp[q], -1.f), 1.f);
    float c0 = __cosf(0.5f * zz), s0 = __sinf(0.5f * zz);
    getU(m, q, u00, u01, u10, u11);
    cplx va = { fmaf(u00.re, c0, u01.re * s0), fmaf(u00.im, c0, u01.im * s0) };
    cplx vb = { fmaf(u10.re, c0, u11.re * s0), fmaf(u10.im, c0, u11.im * s0) };
    cplx f = csel((lane >> (5 - q)) & 1, vb, va);
    laneF = (q == 0) ? f : cmul(laneF, f);
  }
  cplx va_[4], vb_[4];                     // wires 6..9 -> local bits 3..0
  #pragma unroll
  for (int q = 6; q < 10; ++q) {
    float zz = fminf(fmaxf(zp[q], -1.f), 1.f);
    float c0 = __cosf(0.5f * zz), s0 = __sinf(0.5f * zz);
    getU(m, q, u00, u01, u10, u11);
    va_[q - 6] = { fmaf(u00.re, c0, u01.re * s0), fmaf(u00.im, c0, u01.im * s0) };
    vb_[q - 6] = { fmaf(u10.re, c0, u11.re * s0), fmaf(u10.im, c0, u11.im * s0) };
  }

  cplx amp[16];
  {
    cplx P2[4];
    P2[0] = cmul(va_[2], va_[3]);
    P2[1] = cmul(va_[2], vb_[3]);
    P2[2] = cmul(vb_[2], va_[3]);
    P2[3] = cmul(vb_[2], vb_[3]);
    cplx g0 = cmul(laneF, va_[0]);         // wire6 = bit3
    cplx g1 = cmul(laneF, vb_[0]);
    #pragma unroll
    for (int t = 0; t < 16; ++t) {
      cplx t7 = ((t >> 2) & 1) ? vb_[1] : va_[1];
      cplx tt = cmul(t7, P2[t & 3]);
      amp[t] = cmul(((t >> 3) & 1) ? g1 : g0, tt);
    }
  }

  // ---- Layer 1 under layout C^1 (CNOT chains algebraically folded) ----
  #pragma unroll 1
  for (int i = 0; i < 5; ++i)              // b = 9..5, rolled, batched DS
    gate_lane_rt(amp, lane, m, 10 + i, (LX1 >> (6 * i)) & 63, (HIL1 >> (6 * i)) & 63);
  getU(m, 15, u00,u01,u10,u11); gate_mixed<0xB1, 8, 0x3F>(amp, lane, u00,u01,u10,u11);   // b=4
  getU(m, 16, u00,u01,u10,u11); gate_local<0xC, 0x3F, 0x8>(amp, lane, u00,u01,u10,u11);  // b=3
  getU(m, 17, u00,u01,u10,u11); gate_local<0x6, 0x3F, 0xC>(amp, lane, u00,u01,u10,u11);  // b=2
  getU(m, 18, u00,u01,u10,u11); gate_local<0x3, 0x3F, 0xE>(amp, lane, u00,u01,u10,u11);  // b=1
  getU(m, 19, u00,u01,u10,u11); gate_local<0x1, 0x3F, 0xF>(amp, lane, u00,u01,u10,u11);  // b=0

  // ---- Layer 2 under layout C^2 ----
  #pragma unroll 1
  for (int i = 0; i < 4; ++i)              // b = 9..6, rolled, batched DS
    gate_lane_rt(amp, lane, m, 20 + i, (LX2 >> (6 * i)) & 63, (HIL2 >> (6 * i)) & 63);
  getU(m, 24, u00,u01,u10,u11); gate_mixed<0x4E, 8, 0x2A>(amp, lane, u00,u01,u10,u11);   // b=5
  getU(m, 25, u00,u01,u10,u11); gate_mixed<0xB1, 4, 0x15>(amp, lane, u00,u01,u10,u11);   // b=4
  getU(m, 26, u00,u01,u10,u11); gate_local<0xA, 0x2A, 0x8>(amp, lane, u00,u01,u10,u11);  // b=3
  getU(m, 27, u00,u01,u10,u11); gate_local<0x5, 0x15, 0x4>(amp, lane, u00,u01,u10,u11);  // b=2
  getU(m, 28, u00,u01,u10,u11); gate_local<0x2, 0x2A, 0xA>(amp, lane, u00,u01,u10,u11);  // b=1
  getU(m, 29, u00,u01,u10,u11); gate_local<0x1, 0x15, 0x5>(amp, lane, u00,u01,u10,u11);  // b=0

  // ---- measurement under layout C^3 via Walsh-Hadamard transform ----
  float p[16];
  #pragma unroll
  for (int t = 0; t < 16; ++t)
    p[t] = fmaf(amp[t].re, amp[t].re, amp[t].im * amp[t].im);
  // amp[] dead from here -> 32 VGPRs free before w2r is brought in.

  // local 4-bit WHT: p[m] := sum_t p0[t] (-1)^popc(t&m)
  #pragma unroll
  for (int k = 1; k <= 8; k <<= 1) {
    #pragma unroll
    for (int t = 0; t < 16; ++t) {
      if (t & k) continue;
      float a = p[t], b = p[t | k];
      p[t] = a + b; p[t | k] = a - b;
    }
  }

  // ---- prefetch W2 AFTER amps are dead (peak-pressure fix) ----
  float w2r[32];
  #pragma unroll
  for (int jj = 0; jj < 32; ++jj) w2r[jj] = W2[jj * 16 + k16];

  float s1  = (lane & 1)  ? -1.f : 1.f;
  float s2  = (lane & 2)  ? -1.f : 1.f;
  float s4  = (lane & 4)  ? -1.f : 1.f;
  float s8  = (lane & 8)  ? -1.f : 1.f;
  float s16 = (lane & 16) ? -1.f : 1.f;
  float s32 = (lane & 32) ? -1.f : 1.f;
  float B0 = wht6(p[0],   s1,s2,s4,s8,s16,s32);
  float B8 = wht6(p[8],   s1,s2,s4,s8,s16,s32);
  float BC = wht6(p[0xC], s1,s2,s4,s8,s16,s32);
  float B6 = wht6(p[6],   s1,s2,s4,s8,s16,s32);
  float B3 = wht6(p[3],   s1,s2,s4,s8,s16,s32);

  // feats[w] = WHT point at (lane mask | local mask) -- wave-uniform SGPRs
  float feats[10];
  feats[0] = rdlane(B0, 0x20); feats[1] = rdlane(B0, 0x30);
  feats[2] = rdlane(B0, 0x18); feats[3] = rdlane(B0, 0x0C);
  feats[4] = rdlane(B0, 0x26); feats[5] = rdlane(B0, 0x33);
  feats[6] = rdlane(B8, 0x19); feats[7] = rdlane(BC, 0x0C);
  feats[8] = rdlane(B6, 0x26); feats[9] = rdlane(B3, 0x33);

  // ---- MLP: 10->32 tanh ->16 tanh ->1 ; sigmoid*0.2-0.1 == 0.1*tanh(raw/2) ----
  float acc = b1v;
  #pragma unroll
  for (int i = 0; i < NQ; ++i) acc = fmaf(feats[i], w1r[i], acc);
  float h1 = fast_tanh(acc);

  float acc2 = b2v;
  #pragma unroll
  for (int jj = 0; jj < 32; ++jj)
    acc2 = fmaf(rdlane(h1, jj), w2r[jj], acc2);     // readlane: 0 DS
  float h2 = fast_tanh(acc2);

  float vv = h2 * w3v;
  vv += dppf<0xB1>(vv);
  vv += dppf<0x4E>(vv);
  vv += dppf<0x1B>(dppf<0x141>(vv));   // xor4 via DPP chain
  vv += dppf<0x128>(vv);

  if (lane == 0) out[wv] = 0.1f * fast_tanh(0.5f * (vv + b3v));
}

} // namespace

extern "C" void kernel_launch(void* const* d_in, const int* in_sizes, int n_in,
                              void* d_out, int out_size, void* d_ws, size_t ws_size,
                              hipStream_t stream) {
  const float* z   = (const float*)d_in[0];
  const float* wts = (const float*)d_in[1];
  const float* W1  = (const float*)d_in[2];
  const float* b1  = (const float*)d_in[3];
  const float* W2  = (const float*)d_in[4];
  const float* b2  = (const float*)d_in[5];
  const float* W3  = (const float*)d_in[6];
  const float* b3  = (const float*)d_in[7];
  float* out = (float*)d_out;
  (void)d_ws; (void)ws_size;

  int B = in_sizes[0] / NQ;                 // 4096
  hipLaunchKernelGGL(qgan_kernel, dim3(B), dim3(64), 0, stream,
                     z, wts, W1, b1, W2, b2, W3, b3, out, B);
}